// Round 1
// 375.012 us; speedup vs baseline: 1.0440x; 1.0440x over previous
//
#include <hip/hip_runtime.h>
#include <hip/hip_bf16.h>

#define NB 4
#define NH 180
#define NW 320
#define NC 64
#define NSCAN (NB*NH)                    // 720
#define NROWS (NB*NH*NW)                 // 230400
#define NELEM ((size_t)NROWS*NC)         // 14745600

using short8  = __attribute__((ext_vector_type(8))) short;
using floatx4 = __attribute__((ext_vector_type(4))) float;

__device__ __forceinline__ float bflo(unsigned int u) { return __uint_as_float(u << 16); }
__device__ __forceinline__ float bfhi(unsigned int u) { return __uint_as_float(u & 0xffff0000u); }

__device__ __forceinline__ unsigned short fbf(float f) {
    __hip_bfloat16 h = __float2bfloat16(f);
    unsigned short s; __builtin_memcpy(&s, &h, 2); return s;
}
__device__ __forceinline__ unsigned int packbf(float lo, float hi) {
    return (unsigned int)fbf(lo) | ((unsigned int)fbf(hi) << 16);
}

// 0.125 * log2(e) — folded into q_l at projection time (exactly one factor
// per score product regardless of direction), so attn uses exp2f(s) directly.
#define SCALE_LOG2E 0.18033688011112042f

// -------------------------------------------------------------------------
// Kernel 1: fused LayerNorm + 4 projections.
// p=0,1 (q_l,q_r): normal [row][c] bf16 layout.  p=0 additionally pre-scaled
// by 0.125*log2e (score scale folded in).
// p=2,3 (v_l,v_r): TRANSPOSED per-scanline layout vT[scan][c][w] (64x320).
// grid (900, 4), block 256.  mfma_f32_16x16x32_bf16.
// -------------------------------------------------------------------------
__global__ __launch_bounds__(256) void proj_kernel(
    const float* __restrict__ xl, const float* __restrict__ xr,
    const float* __restrict__ lsl, const float* __restrict__ lbl,
    const float* __restrict__ lsr, const float* __restrict__ lbr,
    const float* __restrict__ wql, const float* __restrict__ bql,
    const float* __restrict__ wqr, const float* __restrict__ bqr,
    const float* __restrict__ wvl, const float* __restrict__ bvl,
    const float* __restrict__ wvr, const float* __restrict__ bvr,
    __hip_bfloat16* __restrict__ ql, __hip_bfloat16* __restrict__ qr,
    __hip_bfloat16* __restrict__ vlT, __hip_bfloat16* __restrict__ vrT)
{
    const int p    = blockIdx.y;
    const int t    = threadIdx.x;
    const int row0 = blockIdx.x * 256;

    const float* src  = (p == 0 || p == 2) ? xl : xr;
    const float* Wm   = (p == 0) ? wql : (p == 1) ? wqr : (p == 2) ? wvl : wvr;
    const float* bias = (p == 0) ? bql : (p == 1) ? bqr : (p == 2) ? bvl : bvr;
    __hip_bfloat16* dst = (p == 0) ? ql : (p == 1) ? qr : (p == 2) ? vlT : vrT;
    const bool doLN = (p < 2);
    const float* lns = (p == 0) ? lsl : lsr;
    const float* lnb = (p == 0) ? lbl : lbr;
    const float oscale = (p == 0) ? SCALE_LOG2E : 1.0f;

    __shared__ __align__(16) __hip_bfloat16 sA[256 * 72];   // 36864 B
    __shared__ __align__(16) __hip_bfloat16 sWt[64 * 72];   // 9216 B : sWt[n*72+k] = W[k][n]
    __shared__ float sLs[64], sLb[64], sBias[64];

    if (t < 64) {
        sLs[t]   = doLN ? lns[t] : 1.0f;
        sLb[t]   = doLN ? lnb[t] : 0.0f;
        sBias[t] = bias[t];
    }
    // stage W transposed (fp32 -> bf16)
    {
        const int k  = t >> 2;
        const int c0 = (t & 3) * 16;
        const float4* wrow = (const float4*)(Wm + k * NC + c0);
        float wv[16];
#pragma unroll
        for (int j = 0; j < 4; ++j) {
            float4 w4 = wrow[j];
            wv[4*j] = w4.x; wv[4*j+1] = w4.y; wv[4*j+2] = w4.z; wv[4*j+3] = w4.w;
        }
#pragma unroll
        for (int j = 0; j < 16; ++j)
            sWt[(c0 + j) * 72 + k] = __float2bfloat16(wv[j]);
    }
    __syncthreads();

    // Phase 1: thread t owns row (row0 + t): fp32 load, (LN), bf16 pack into sA
    {
        const float4* x4 = (const float4*)(src + (size_t)(row0 + t) * NC);
        float f[64];
#pragma unroll
        for (int j = 0; j < 16; ++j) {
            float4 v = x4[j];
            f[4*j] = v.x; f[4*j+1] = v.y; f[4*j+2] = v.z; f[4*j+3] = v.w;
        }
        if (doLN) {
            float s = 0.f, s2 = 0.f;
#pragma unroll
            for (int c = 0; c < 64; ++c) { s += f[c]; s2 = fmaf(f[c], f[c], s2); }
            const float mu   = s * (1.0f / 64.0f);
            const float var  = s2 * (1.0f / 64.0f) - mu * mu;
            const float rstd = rsqrtf(var + 1e-6f);
#pragma unroll
            for (int c = 0; c < 64; ++c) f[c] = (f[c] - mu) * rstd * sLs[c] + sLb[c];
        }
        unsigned int* arow = (unsigned int*)&sA[t * 72];
#pragma unroll
        for (int j = 0; j < 32; ++j) arow[j] = packbf(f[2*j], f[2*j+1]);
    }
    __syncthreads();

    // Phase 2: MFMA.
    const int lane = t & 63;
    const int wv_  = t >> 6;
    const int quad = lane >> 4;
    const int mn   = lane & 15;

    short8 bfr[4][2];
#pragma unroll
    for (int nt = 0; nt < 4; ++nt)
#pragma unroll
        for (int ks = 0; ks < 2; ++ks)
            bfr[nt][ks] = *(const short8*)&sWt[(nt * 16 + mn) * 72 + ks * 32 + quad * 8];

#pragma unroll
    for (int mt = 0; mt < 4; ++mt) {
        const int rl = wv_ * 64 + mt * 16 + mn;
        short8 a0 = *(const short8*)&sA[rl * 72 +      quad * 8];
        short8 a1 = *(const short8*)&sA[rl * 72 + 32 + quad * 8];
#pragma unroll
        for (int nt = 0; nt < 4; ++nt) {
            floatx4 c = {0.f, 0.f, 0.f, 0.f};
            c = __builtin_amdgcn_mfma_f32_16x16x32_bf16(a0, bfr[nt][0], c, 0, 0, 0);
            c = __builtin_amdgcn_mfma_f32_16x16x32_bf16(a1, bfr[nt][1], c, 0, 0, 0);
            const int col = nt * 16 + mn;
            const float bb = sBias[col];
            if (p < 2) {
#pragma unroll
                for (int i = 0; i < 4; ++i) {
                    const int rowl = wv_ * 64 + mt * 16 + quad * 4 + i;
                    dst[(size_t)(row0 + rowl) * NC + col] =
                        __float2bfloat16((c[i] + bb) * oscale);
                }
            } else {
#pragma unroll
                for (int i = 0; i < 4; ++i) {
                    const unsigned grow = (unsigned)(row0 + wv_ * 64 + mt * 16 + quad * 4 + i);
                    const unsigned sc   = grow / 320u;
                    const unsigned wr   = grow - sc * 320u;
                    dst[(size_t)sc * (NC * NW) + (unsigned)col * NW + wr] =
                        __float2bfloat16(c[i] + bb);
                }
            }
        }
    }
}

// -------------------------------------------------------------------------
// Kernel 2: MFMA bidirectional scanline attention (no-max flash: logits
// bounded, plain sum-of-exp).  grid (5, 720, 2) remapped bijectively so each
// XCD owns whole scanline groups (L2 reuse of K/VT/Q across the 5 m-tiles
// and both directions).  block 256.
// dir 0: Q=q_l, K=q_r, V=v_r (row softmax)  -> out0 = x_l + beta * O/rs
// dir 1: Q=q_r, K=q_l, V=v_l (col softmax)  -> out1 = x_r + gamma * O/rs
//
// Swapped QK^T: S^T = mfma(K_frag, Q_frag) puts P row-local per lane ->
// packed b64 P stores, in-register row-sum, no sP re-read.
// K/VT staged via register prefetch (next chunk's loads issued before
// compute, hidden under MFMA+exp).  sP overlays dead sQ -> 27.9 KB LDS,
// 5 blocks/CU.
// -------------------------------------------------------------------------
__global__ __launch_bounds__(256) void attn_kernel(
    const __hip_bfloat16* __restrict__ ql, const __hip_bfloat16* __restrict__ qr,
    const __hip_bfloat16* __restrict__ vlT, const __hip_bfloat16* __restrict__ vrT,
    const float* __restrict__ xl, const float* __restrict__ xr,
    const float* __restrict__ beta, const float* __restrict__ gamma,
    float* __restrict__ out)
{
    // bijective XCD-aware remap: 7200 blocks = 8 XCDs * 900.
    const int flat = blockIdx.x + 5 * (blockIdx.y + 720 * blockIdx.z);
    const int g    = (flat & 7) * 900 + (flat >> 3);
    const int mt   = g % 5;            // 0..4
    const int s2   = g / 5;            // 0..1439
    const int p    = s2 & 1;           // 0..1
    const int scan = s2 >> 1;          // 0..719

    const int t    = threadIdx.x;
    const int lane = t & 63;
    const int w    = t >> 6;
    const int quad = lane >> 4;
    const int mn   = lane & 15;
    const int m0   = mt * 64;

    const __hip_bfloat16* Q  = (p ? qr  : ql ) + (size_t)scan * (NW * NC);
    const __hip_bfloat16* K  = (p ? ql  : qr ) + (size_t)scan * (NW * NC);
    const __hip_bfloat16* VT = (p ? vlT : vrT) + (size_t)scan * (NC * NW);
    const float* xS = p ? xr : xl;
    const float* gv = p ? gamma : beta;

    __shared__ __align__(16) __hip_bfloat16 sQP[64 * 72];   // 9216 B: sQ, then sP
    __shared__ __align__(16) char sU[18432];                // sK+sVt  OR  sO
    __shared__ float sRS[64];
    __hip_bfloat16* sK  = (__hip_bfloat16*)sU;              // 64*72 bf16
    __hip_bfloat16* sVt = (__hip_bfloat16*)(sU + 9216);     // 64*72 bf16
    float* sO = (float*)sU;                                  // 64*68 fp32 (17408 B)

    const int sr  = t >> 2;            // staging row 0..63
    const int sc0 = (t & 3) * 16;      // staging col offset (elements)

    // prefetch chunk 0 (K rows 0..63, VT cols 0..63) into registers
    uint4 rk0, rk1, rv0, rv1;
    {
        const uint4* gk = (const uint4*)(K + (size_t)sr * NC + sc0);
        rk0 = gk[0]; rk1 = gk[1];
        const uint4* gt = (const uint4*)(VT + (size_t)sr * NW + sc0);
        rv0 = gt[0]; rv1 = gt[1];
    }

    // stage sQ (rows m0..m0+63)
    {
        const uint4* gq = (const uint4*)(Q + (size_t)(m0 + sr) * NC + sc0);
        uint4 a = gq[0], b = gq[1];
        uint4* d = (uint4*)&sQP[sr * 72 + sc0];
        d[0] = a; d[1] = b;
    }
    __syncthreads();

    // preload Q B-frags: wave w owns Q rows w*16 .. w*16+15 (col=mn, k=quad*8+j)
    const short8 qa0 = *(const short8*)&sQP[(w * 16 + mn) * 72 +      quad * 8];
    const short8 qa1 = *(const short8*)&sQP[(w * 16 + mn) * 72 + 32 + quad * 8];

    floatx4 acc[4];
#pragma unroll
    for (int nt = 0; nt < 4; ++nt) acc[nt] = (floatx4){0.f, 0.f, 0.f, 0.f};
    float rs = 0.f;

    for (int rb = 0; rb < NW; rb += 64) {
        __syncthreads();   // prior chunk's sK/sVt reads (and initial qa reads) done
        {
            uint4* dk = (uint4*)&sK [sr * 72 + sc0]; dk[0] = rk0; dk[1] = rk1;
            uint4* dv = (uint4*)&sVt[sr * 72 + sc0]; dv[0] = rv0; dv[1] = rv1;
        }
        __syncthreads();   // sK/sVt ready

        // issue next chunk's global loads now; they complete under the compute
        if (rb + 64 < NW) {
            const uint4* gk = (const uint4*)(K + (size_t)(rb + 64 + sr) * NC + sc0);
            rk0 = gk[0]; rk1 = gk[1];
            const uint4* gt = (const uint4*)(VT + (size_t)sr * NW + (rb + 64) + sc0);
            rv0 = gt[0]; rv1 = gt[1];
        }

        __builtin_amdgcn_s_setprio(1);
        // swapped QK^T: S^T = K_tile * Q^T.  Lane (quad,mn) holds
        // P[m = w*16+mn][r = rt*16 + quad*4 + i]  -> pack pairs, b64 store,
        // and row-sum accumulates in-register (r partitioned across quads).
#pragma unroll
        for (int rt = 0; rt < 4; ++rt) {
            short8 ka0 = *(const short8*)&sK[(rt * 16 + mn) * 72 +      quad * 8];
            short8 ka1 = *(const short8*)&sK[(rt * 16 + mn) * 72 + 32 + quad * 8];
            floatx4 s = {0.f, 0.f, 0.f, 0.f};
            s = __builtin_amdgcn_mfma_f32_16x16x32_bf16(ka0, qa0, s, 0, 0, 0);
            s = __builtin_amdgcn_mfma_f32_16x16x32_bf16(ka1, qa1, s, 0, 0, 0);
            const unsigned c0 = packbf(exp2f(s[0]), exp2f(s[1]));
            const unsigned c1 = packbf(exp2f(s[2]), exp2f(s[3]));
            rs += bflo(c0) + bfhi(c0) + bflo(c1) + bfhi(c1);
            uint2 pk; pk.x = c0; pk.y = c1;
            *(uint2*)&sQP[(w * 16 + mn) * 72 + rt * 16 + quad * 4] = pk;
        }

        // PV (contract r): A = P rows (m=mn), B = Vt rows (n-col c).
        // sP slab is wave-local -> no barrier, compiler's lgkmcnt orders it.
#pragma unroll
        for (int ks = 0; ks < 2; ++ks) {
            short8 pa = *(const short8*)&sQP[(w * 16 + mn) * 72 + ks * 32 + quad * 8];
#pragma unroll
            for (int nt = 0; nt < 4; ++nt) {
                short8 vb = *(const short8*)&sVt[(nt * 16 + mn) * 72 + ks * 32 + quad * 8];
                acc[nt] = __builtin_amdgcn_mfma_f32_16x16x32_bf16(pa, vb, acc[nt], 0, 0, 0);
            }
        }
        __builtin_amdgcn_s_setprio(0);
    }

    // finish row sums: quads hold disjoint r-subsets of row (w*16+mn)
    rs += __shfl_xor(rs, 16);
    rs += __shfl_xor(rs, 32);

    __syncthreads();   // all PV reads of sVt done -> sU reusable as sO

    if (lane < 16) sRS[w * 16 + lane] = 1.0f / rs;   // lane<16 => mn==lane
#pragma unroll
    for (int nt = 0; nt < 4; ++nt)
#pragma unroll
        for (int i = 0; i < 4; ++i)
            sO[(w * 16 + quad * 4 + i) * 68 + nt * 16 + mn] = acc[nt][i];
    __syncthreads();

    // epilogue: coalesced fp32 out = x + (O/rs) * gv
    {
        const int m = t >> 2, c0 = (t & 3) * 16;
        const float inv = sRS[m];
        const int grow = scan * NW + m0 + m;
        const float4* xg = (const float4*)(xS + (size_t)grow * NC + c0);
        const float4* gg = (const float4*)(gv + c0);
        const float4* so = (const float4*)&sO[m * 68 + c0];
        float4* og = (float4*)(out + (p ? NELEM : (size_t)0) + (size_t)grow * NC + c0);
#pragma unroll
        for (int j = 0; j < 4; ++j) {
            float4 xv = xg[j];
            float4 gvv = gg[j];
            float4 ov = so[j];
            float4 o;
            o.x = xv.x + ov.x * inv * gvv.x;
            o.y = xv.y + ov.y * inv * gvv.y;
            o.z = xv.z + ov.z * inv * gvv.z;
            o.w = xv.w + ov.w * inv * gvv.w;
            og[j] = o;
        }
    }
}

extern "C" void kernel_launch(void* const* d_in, const int* in_sizes, int n_in,
                              void* d_out, int out_size, void* d_ws, size_t ws_size,
                              hipStream_t stream)
{
    const float* xl  = (const float*)d_in[0];
    const float* xr  = (const float*)d_in[1];
    const float* lsl = (const float*)d_in[2];
    const float* lbl = (const float*)d_in[3];
    const float* lsr = (const float*)d_in[4];
    const float* lbr = (const float*)d_in[5];
    const float* wql = (const float*)d_in[6];
    const float* bql = (const float*)d_in[7];
    const float* wqr = (const float*)d_in[8];
    const float* bqr = (const float*)d_in[9];
    const float* wvl = (const float*)d_in[10];
    const float* bvl = (const float*)d_in[11];
    const float* wvr = (const float*)d_in[12];
    const float* bvr = (const float*)d_in[13];
    const float* beta  = (const float*)d_in[14];
    const float* gamma = (const float*)d_in[15];

    __hip_bfloat16* ws   = (__hip_bfloat16*)d_ws;
    __hip_bfloat16* ql_  = ws;
    __hip_bfloat16* qr_  = ws + NELEM;
    __hip_bfloat16* vlT_ = ws + 2 * NELEM;
    __hip_bfloat16* vrT_ = ws + 3 * NELEM;

    proj_kernel<<<dim3(NROWS / 256, 4, 1), 256, 0, stream>>>(
        xl, xr, lsl, lbl, lsr, lbr, wql, bql, wqr, bqr, wvl, bvl, wvr, bvr,
        ql_, qr_, vlT_, vrT_);

    attn_kernel<<<dim3(5, NSCAN, 2), 256, 0, stream>>>(
        ql_, qr_, vlT_, vrT_, xl, xr, beta, gamma, (float*)d_out);
}